// Round 5
// baseline (498.806 us; speedup 1.0000x reference)
//
#include <hip/hip_runtime.h>
#include <hip/hip_bf16.h>
#include <stdint.h>

// MoE: N=8192 tokens, H=1024, E=16 experts (top-2), I=512, shared IS=2048.
// R5: BK=64 K-loops with XOR-swizzled LDS staging (conflict-free fragment
//     reads), sg2 retiled 128x64 (1024 blocks), merged cvt kernel with
//     ws_size-dependent placement of expert-weight bf16 copies.

#define N_TOK 8192
#define HDIM 1024
#define NEXP 16
#define IEXP 512
#define ISH 2048

typedef __bf16 bf16x8 __attribute__((ext_vector_type(8)));
typedef float f32x4 __attribute__((ext_vector_type(4)));

// ---- ws layout (bytes) ----
#define OFF_XBF   ((size_t)0)            // 16,777,216 (dead after eg1 -> wdn_bf fallback)
#define OFF_WSG   ((size_t)16777216)     // 4,194,304
#define OFF_WSU   ((size_t)20971520)
#define OFF_WSD   ((size_t)25165824)
#define OFF_SH    ((size_t)29360128)     // 33,554,432 (sh; dead after sg2 -> wgu_bf fallback; -> eout after eg1)
#define OFF_HEXP  ((size_t)62914560)     // 16,777,216
#define OFF_IDS   ((size_t)79691776)     // 524,288
#define OFF_META  ((size_t)80216064)     // cnt[16]@0, off[17]@64, probs_sum[16]@144
#define OFF_SIG   ((size_t)80216320)     // 32,768
#define OFF_LG    ((size_t)80249088)     // 1,048,576
#define OFF_SLOT  ((size_t)81297664)     // 65,536
#define OFF_TWAB  ((size_t)81363200)     // 65,536
#define OFF_WGU2  ((size_t)81428736)     // 33,554,432 (only if ws_size allows)
#define OFF_WDN2  ((size_t)114983168)    // 16,777,216
#define WS_NEED_ROOMY ((size_t)131760384)

static __device__ __forceinline__ unsigned short f2bf(float f) {
  unsigned int u = __float_as_uint(f);
  u += 0x7fffu + ((u >> 16) & 1u);
  return (unsigned short)(u >> 16);
}
static __device__ __forceinline__ int pack_bf2(float a, float b) {
  return (int)f2bf(a) | ((int)f2bf(b) << 16);
}
static __device__ __forceinline__ float bf2f(unsigned short u) {
  return __uint_as_float(((unsigned int)u) << 16);
}
static __device__ __forceinline__ void gl_lds16(const void* g, void* l) {
  __builtin_amdgcn_global_load_lds(
      (const __attribute__((address_space(1))) unsigned int*)g,
      (__attribute__((address_space(3))) unsigned int*)l, 16, 0, 0);
}

__global__ void cvt_kernel(const float* __restrict__ src,
                           unsigned short* __restrict__ dst, int n4) {
  int i = blockIdx.x * 256 + threadIdx.x;
  if (i >= n4) return;
  float4 v = ((const float4*)src)[i];
  uint2 o;
  o.x = (unsigned)pack_bf2(v.x, v.y);
  o.y = (unsigned)pack_bf2(v.z, v.w);
  ((uint2*)dst)[i] = o;
}

// up to 5 segments, counts in float4 units (0 = skip)
__global__ void cvt5_kernel(const float* s0, unsigned short* d0, int c0,
                            const float* s1, unsigned short* d1, int c1,
                            const float* s2, unsigned short* d2, int c2,
                            const float* s3, unsigned short* d3, int c3,
                            const float* s4, unsigned short* d4, int c4) {
  int i = blockIdx.x * 256 + threadIdx.x;
  const float* s; unsigned short* d;
  if (i < c0) { s = s0; d = d0; }
  else { i -= c0;
  if (i < c1) { s = s1; d = d1; }
  else { i -= c1;
  if (i < c2) { s = s2; d = d2; }
  else { i -= c2;
  if (i < c3) { s = s3; d = d3; }
  else { i -= c3;
  if (i < c4) { s = s4; d = d4; }
  else return; }}}}
  float4 v = ((const float4*)s)[i];
  uint2 o;
  o.x = (unsigned)pack_bf2(v.x, v.y);
  o.y = (unsigned)pack_bf2(v.z, v.w);
  ((uint2*)d)[i] = o;
}

// ---- logits (wave/token) + fused X->bf16
__global__ __launch_bounds__(256) void logits_kernel(
    const float* __restrict__ X, const float* __restrict__ GW,
    const float* __restrict__ SEGW, float* __restrict__ LG,
    unsigned short* __restrict__ XBF) {
  int wid = threadIdx.x >> 6, lane = threadIdx.x & 63;
  int tok = blockIdx.x * 4 + wid;
  const float* xr = X + (size_t)tok * HDIM;
  unsigned short* xw = XBF + (size_t)tok * HDIM;
  float xv[16];
#pragma unroll
  for (int i = 0; i < 16; i++) xv[i] = xr[lane + 64 * i];
#pragma unroll
  for (int i = 0; i < 16; i++) xw[lane + 64 * i] = f2bf(xv[i]);
  float myv = 0.f;
#pragma unroll
  for (int e = 0; e < 17; e++) {
    const float* wr = (e < 16) ? (GW + (size_t)e * HDIM) : SEGW;
    float p = 0.f;
#pragma unroll
    for (int i = 0; i < 16; i++) p += xv[i] * wr[lane + 64 * i];
#pragma unroll
    for (int off = 32; off >= 1; off >>= 1) p += __shfl_xor(p, off, 64);
    if (lane == e) myv = p;
  }
  if (lane < 17) LG[(size_t)tok * 32 + lane] = myv;
}

// ---- route: softmax/top2/scatter, block-aggregated atomics
__global__ __launch_bounds__(256) void route_kernel(
    const float* __restrict__ LG, int* __restrict__ cnt,
    float* __restrict__ pps, int* __restrict__ ids,
    int* __restrict__ slotAB, float* __restrict__ twAB,
    float* __restrict__ sig) {
  __shared__ int lcnt[16];
  __shared__ int lbase[16];
  __shared__ float lps[16];
  int tid = threadIdx.x;
  int tok = blockIdx.x * 256 + tid;
  if (tid < 16) { lcnt[tid] = 0; lps[tid] = 0.f; }
  __syncthreads();
  const float4* row = (const float4*)(LG + (size_t)tok * 32);
  float4 v0 = row[0], v1 = row[1], v2 = row[2], v3 = row[3];
  float g16 = row[4].x;
  float lg[16] = {v0.x, v0.y, v0.z, v0.w, v1.x, v1.y, v1.z, v1.w,
                  v2.x, v2.y, v2.z, v2.w, v3.x, v3.y, v3.z, v3.w};
  float mx = lg[0];
#pragma unroll
  for (int e = 1; e < 16; e++) mx = fmaxf(mx, lg[e]);
  float pr[16], s = 0.f;
#pragma unroll
  for (int e = 0; e < 16; e++) { pr[e] = __expf(lg[e] - mx); s += pr[e]; }
  float inv_s = 1.f / s;
  float p1 = -1.f, p2 = -1.f; int i1 = 0, i2 = 0;
#pragma unroll
  for (int e = 0; e < 16; e++) {
    if (pr[e] > p1) { p2 = p1; i2 = i1; p1 = pr[e]; i1 = e; }
    else if (pr[e] > p2) { p2 = pr[e]; i2 = e; }
  }
  float wsum = p1 + p2;
  int s1 = atomicAdd(&lcnt[i1], 1);
  int s2 = atomicAdd(&lcnt[i2], 1);
#pragma unroll
  for (int e = 0; e < 16; e++) atomicAdd(&lps[e], pr[e] * inv_s);
  sig[tok] = 1.f / (1.f + __expf(-g16));
  __syncthreads();
  if (tid < 16) {
    lbase[tid] = atomicAdd(&cnt[tid], lcnt[tid]);
    atomicAdd(&pps[tid], lps[tid]);
  }
  __syncthreads();
  int sl1 = lbase[i1] + s1, sl2 = lbase[i2] + s2;
  ids[i1 * N_TOK + sl1] = tok;
  ids[i2 * N_TOK + sl2] = tok;
  slotAB[tok * 2]     = (i1 << 14) | sl1;
  slotAB[tok * 2 + 1] = (i2 << 14) | sl2;
  twAB[tok * 2]     = p1 / wsum;
  twAB[tok * 2 + 1] = p2 / wsum;
}

__global__ void offs_aux_kernel(const int* __restrict__ cnt, int* __restrict__ off,
                                const float* __restrict__ probs_sum,
                                float* __restrict__ out_aux) {
  if (threadIdx.x == 0 && blockIdx.x == 0) {
    int run = 0; float aux = 0.f;
    for (int e = 0; e < NEXP; e++) {
      off[e] = run; run += cnt[e];
      aux += ((float)cnt[e] / (float)(N_TOK * 2)) * (probs_sum[e] / (float)N_TOK);
    }
    off[16] = run;
    *out_aux = (float)NEXP * aux;
  }
}

// XOR-swizzle convention for 64-col tiles staged via gl_lds16:
//   stage: thread t -> LDS row (t>>3), chunk (t&7); global col chunk = (t&7)^((t>>3)&7)
//   read:  row R, want col chunk c2=kk*4+q (q=lane>>4): LDS chunk = c2^(R&7) = c2^(fr&7)

// ---- shared gemm1: H = silu(X@Wg^T)*(X@Wu^T); 128m x 64n, BK=64
__global__ __launch_bounds__(256) void shared_gemm1_kernel(
    const unsigned short* __restrict__ X, const unsigned short* __restrict__ Wg,
    const unsigned short* __restrict__ Wu, unsigned short* __restrict__ H) {
  __shared__ __align__(16) unsigned short As[128 * 64];
  __shared__ __align__(16) unsigned short Bs1[64 * 64];
  __shared__ __align__(16) unsigned short Bs2[64 * 64];
  int m0 = blockIdx.y * 128, n0 = blockIdx.x * 64;
  int t = threadIdx.x, lane = t & 63, w = t >> 6;
  int wm = (w & 1) * 64, wn = (w >> 1) * 32;
  int srow = t >> 3;
  int scol = (((t & 7) ^ (srow & 7)) * 8);
  const unsigned short* apA[4];
#pragma unroll
  for (int r = 0; r < 4; r++) apA[r] = X + (size_t)(m0 + r * 32 + srow) * HDIM + scol;
  const unsigned short* apB1[2];
  const unsigned short* apB2[2];
#pragma unroll
  for (int r = 0; r < 2; r++) {
    apB1[r] = Wg + (size_t)(n0 + r * 32 + srow) * HDIM + scol;
    apB2[r] = Wu + (size_t)(n0 + r * 32 + srow) * HDIM + scol;
  }
  int fr = lane & 15, q = lane >> 4, sw = fr & 7;
  int fo0 = ((q ^ sw) * 8), fo1 = (((4 + q) ^ sw) * 8);
  f32x4 z = {0.f, 0.f, 0.f, 0.f};
  f32x4 accg[4][2], accu[4][2];
#pragma unroll
  for (int i = 0; i < 4; i++)
#pragma unroll
    for (int j = 0; j < 2; j++) { accg[i][j] = z; accu[i][j] = z; }
  for (int k0 = 0; k0 < HDIM; k0 += 64) {
    __syncthreads();
#pragma unroll
    for (int r = 0; r < 4; r++) gl_lds16(apA[r] + k0, &As[r * 2048 + t * 8]);
#pragma unroll
    for (int r = 0; r < 2; r++) {
      gl_lds16(apB1[r] + k0, &Bs1[r * 2048 + t * 8]);
      gl_lds16(apB2[r] + k0, &Bs2[r * 2048 + t * 8]);
    }
    __syncthreads();
#pragma unroll
    for (int kk = 0; kk < 2; kk++) {
      int fo = kk ? fo1 : fo0;
      bf16x8 af[4], bg[2], bu[2];
#pragma unroll
      for (int i = 0; i < 4; i++) af[i] = *(const bf16x8*)&As[(wm + i * 16 + fr) * 64 + fo];
#pragma unroll
      for (int j = 0; j < 2; j++) {
        bg[j] = *(const bf16x8*)&Bs1[(wn + j * 16 + fr) * 64 + fo];
        bu[j] = *(const bf16x8*)&Bs2[(wn + j * 16 + fr) * 64 + fo];
      }
#pragma unroll
      for (int i = 0; i < 4; i++)
#pragma unroll
        for (int j = 0; j < 2; j++) {
          accg[i][j] = __builtin_amdgcn_mfma_f32_16x16x32_bf16(af[i], bg[j], accg[i][j], 0, 0, 0);
          accu[i][j] = __builtin_amdgcn_mfma_f32_16x16x32_bf16(af[i], bu[j], accu[i][j], 0, 0, 0);
        }
    }
  }
  int col = lane & 15, rq = (lane >> 4) * 4;
#pragma unroll
  for (int i = 0; i < 4; i++)
#pragma unroll
    for (int j = 0; j < 2; j++)
#pragma unroll
      for (int r = 0; r < 4; r++) {
        int mm = m0 + wm + i * 16 + rq + r;
        int nn = n0 + wn + j * 16 + col;
        float g = accg[i][j][r], u = accu[i][j][r];
        float h = g / (1.f + __expf(-g)) * u;
        H[(size_t)mm * ISH + nn] = f2bf(h);
      }
}

// ---- shared gemm2: Out = (H@Wd^T)*sig; 128m x 64n, BK=64 (1024 blocks)
__global__ __launch_bounds__(256) void shared_gemm2_kernel(
    const unsigned short* __restrict__ H, const unsigned short* __restrict__ Wd,
    const float* __restrict__ sig, float* __restrict__ Out) {
  __shared__ __align__(16) unsigned short As[128 * 64];
  __shared__ __align__(16) unsigned short Bs[64 * 64];
  int m0 = blockIdx.y * 128, n0 = blockIdx.x * 64;
  int t = threadIdx.x, lane = t & 63, w = t >> 6;
  int wm = (w & 1) * 64, wn = (w >> 1) * 32;
  int srow = t >> 3;
  int scol = (((t & 7) ^ (srow & 7)) * 8);
  const unsigned short* apA[4];
#pragma unroll
  for (int r = 0; r < 4; r++) apA[r] = H + (size_t)(m0 + r * 32 + srow) * ISH + scol;
  const unsigned short* apB[2];
#pragma unroll
  for (int r = 0; r < 2; r++) apB[r] = Wd + (size_t)(n0 + r * 32 + srow) * ISH + scol;
  int fr = lane & 15, q = lane >> 4, sw = fr & 7;
  int fo0 = ((q ^ sw) * 8), fo1 = (((4 + q) ^ sw) * 8);
  f32x4 z = {0.f, 0.f, 0.f, 0.f};
  f32x4 acc[4][2];
#pragma unroll
  for (int i = 0; i < 4; i++)
#pragma unroll
    for (int j = 0; j < 2; j++) acc[i][j] = z;
  for (int k0 = 0; k0 < ISH; k0 += 64) {
    __syncthreads();
#pragma unroll
    for (int r = 0; r < 4; r++) gl_lds16(apA[r] + k0, &As[r * 2048 + t * 8]);
#pragma unroll
    for (int r = 0; r < 2; r++) gl_lds16(apB[r] + k0, &Bs[r * 2048 + t * 8]);
    __syncthreads();
#pragma unroll
    for (int kk = 0; kk < 2; kk++) {
      int fo = kk ? fo1 : fo0;
      bf16x8 af[4], bfr[2];
#pragma unroll
      for (int i = 0; i < 4; i++) af[i] = *(const bf16x8*)&As[(wm + i * 16 + fr) * 64 + fo];
#pragma unroll
      for (int j = 0; j < 2; j++) bfr[j] = *(const bf16x8*)&Bs[(wn + j * 16 + fr) * 64 + fo];
#pragma unroll
      for (int i = 0; i < 4; i++)
#pragma unroll
        for (int j = 0; j < 2; j++)
          acc[i][j] = __builtin_amdgcn_mfma_f32_16x16x32_bf16(af[i], bfr[j], acc[i][j], 0, 0, 0);
    }
  }
  int col = lane & 15, rq = (lane >> 4) * 4;
#pragma unroll
  for (int i = 0; i < 4; i++)
#pragma unroll
    for (int r = 0; r < 4; r++) {
      int mm = m0 + wm + i * 16 + rq + r;
      float sg = sig[mm];
#pragma unroll
      for (int j = 0; j < 2; j++) {
        int nn = n0 + wn + j * 16 + col;
        Out[(size_t)mm * HDIM + nn] = acc[i][j][r] * sg;
      }
    }
}

// ---- expert gemm1 (grouped, gathered A): Hexp = silu(g)*u; 128m x 64n, BK=64
__global__ __launch_bounds__(256) void exp_gemm1_kernel(
    const unsigned short* __restrict__ X, const unsigned short* __restrict__ WGUb,
    const int* __restrict__ ids, const int* __restrict__ cnt,
    const int* __restrict__ off, unsigned short* __restrict__ Hexp) {
  int e = blockIdx.z;
  int ne = cnt[e];
  int m0 = blockIdx.y * 128;
  if (m0 >= ne) return;
  __shared__ __align__(16) unsigned short As[128 * 64];
  __shared__ __align__(16) unsigned short Bs1[64 * 64];
  __shared__ __align__(16) unsigned short Bs2[64 * 64];
  int n0 = blockIdx.x * 64;
  const int* eids = ids + e * N_TOK;
  int base = off[e];
  int t = threadIdx.x, lane = t & 63, w = t >> 6;
  int wm = (w & 1) * 64, wn = (w >> 1) * 32;
  int srow = t >> 3;
  int scol = (((t & 7) ^ (srow & 7)) * 8);
  const unsigned short* apA[4];
#pragma unroll
  for (int r = 0; r < 4; r++) {
    int slot = m0 + r * 32 + srow;
    int tok = (slot < ne) ? eids[slot] : 0;
    apA[r] = X + (size_t)tok * HDIM + scol;
  }
  const unsigned short* apB1[2];
  const unsigned short* apB2[2];
#pragma unroll
  for (int r = 0; r < 2; r++) {
    apB1[r] = WGUb + ((size_t)e * 1024 + n0 + r * 32 + srow) * HDIM + scol;
    apB2[r] = WGUb + ((size_t)e * 1024 + 512 + n0 + r * 32 + srow) * HDIM + scol;
  }
  int fr = lane & 15, q = lane >> 4, sw = fr & 7;
  int fo0 = ((q ^ sw) * 8), fo1 = (((4 + q) ^ sw) * 8);
  f32x4 z = {0.f, 0.f, 0.f, 0.f};
  f32x4 accg[4][2], accu[4][2];
#pragma unroll
  for (int i = 0; i < 4; i++)
#pragma unroll
    for (int j = 0; j < 2; j++) { accg[i][j] = z; accu[i][j] = z; }
  for (int k0 = 0; k0 < HDIM; k0 += 64) {
    __syncthreads();
#pragma unroll
    for (int r = 0; r < 4; r++) gl_lds16(apA[r] + k0, &As[r * 2048 + t * 8]);
#pragma unroll
    for (int r = 0; r < 2; r++) {
      gl_lds16(apB1[r] + k0, &Bs1[r * 2048 + t * 8]);
      gl_lds16(apB2[r] + k0, &Bs2[r * 2048 + t * 8]);
    }
    __syncthreads();
#pragma unroll
    for (int kk = 0; kk < 2; kk++) {
      int fo = kk ? fo1 : fo0;
      bf16x8 af[4], bg[2], bu[2];
#pragma unroll
      for (int i = 0; i < 4; i++) af[i] = *(const bf16x8*)&As[(wm + i * 16 + fr) * 64 + fo];
#pragma unroll
      for (int j = 0; j < 2; j++) {
        bg[j] = *(const bf16x8*)&Bs1[(wn + j * 16 + fr) * 64 + fo];
        bu[j] = *(const bf16x8*)&Bs2[(wn + j * 16 + fr) * 64 + fo];
      }
#pragma unroll
      for (int i = 0; i < 4; i++)
#pragma unroll
        for (int j = 0; j < 2; j++) {
          accg[i][j] = __builtin_amdgcn_mfma_f32_16x16x32_bf16(af[i], bg[j], accg[i][j], 0, 0, 0);
          accu[i][j] = __builtin_amdgcn_mfma_f32_16x16x32_bf16(af[i], bu[j], accu[i][j], 0, 0, 0);
        }
    }
  }
  int col = lane & 15, rq = (lane >> 4) * 4;
#pragma unroll
  for (int i = 0; i < 4; i++)
#pragma unroll
    for (int j = 0; j < 2; j++)
#pragma unroll
      for (int r = 0; r < 4; r++) {
        int slot = m0 + wm + i * 16 + rq + r;
        if (slot < ne) {
          int nn = n0 + wn + j * 16 + col;
          float g = accg[i][j][r], u = accu[i][j][r];
          float h = g / (1.f + __expf(-g)) * u;
          Hexp[(size_t)(base + slot) * IEXP + nn] = f2bf(h);
        }
      }
}

// ---- expert gemm2 (grouped): Eout = Hexp@Wd^T (raw bf16); 128x128, BK=64
__global__ __launch_bounds__(256) void exp_gemm2_kernel(
    const unsigned short* __restrict__ Hexp, const unsigned short* __restrict__ WDb,
    const int* __restrict__ cnt, const int* __restrict__ off,
    unsigned short* __restrict__ Eout) {
  int e = blockIdx.z;
  int ne = cnt[e];
  int m0 = blockIdx.y * 128;
  if (m0 >= ne) return;
  __shared__ __align__(16) unsigned short As[128 * 64];
  __shared__ __align__(16) unsigned short Bs[128 * 64];
  int n0 = blockIdx.x * 128;
  int base = off[e];
  int t = threadIdx.x, lane = t & 63, w = t >> 6;
  int wm = (w & 1) * 64, wn = (w >> 1) * 64;
  int srow = t >> 3;
  int scol = (((t & 7) ^ (srow & 7)) * 8);
  const unsigned short* apA[4];
#pragma unroll
  for (int r = 0; r < 4; r++) {
    int ra = base + m0 + r * 32 + srow;
    if (ra > 16383) ra = 16383;
    apA[r] = Hexp + (size_t)ra * IEXP + scol;
  }
  const unsigned short* apB[4];
#pragma unroll
  for (int r = 0; r < 4; r++)
    apB[r] = WDb + ((size_t)e * HDIM + n0 + r * 32 + srow) * IEXP + scol;
  int fr = lane & 15, q = lane >> 4, sw = fr & 7;
  int fo0 = ((q ^ sw) * 8), fo1 = (((4 + q) ^ sw) * 8);
  f32x4 z = {0.f, 0.f, 0.f, 0.f};
  f32x4 acc[4][4];
#pragma unroll
  for (int i = 0; i < 4; i++)
#pragma unroll
    for (int j = 0; j < 4; j++) acc[i][j] = z;
  for (int k0 = 0; k0 < IEXP; k0 += 64) {
    __syncthreads();
#pragma unroll
    for (int r = 0; r < 4; r++) {
      gl_lds16(apA[r] + k0, &As[r * 2048 + t * 8]);
      gl_lds16(apB[r] + k0, &Bs[r * 2048 + t * 8]);
    }
    __syncthreads();
#pragma unroll
    for (int kk = 0; kk < 2; kk++) {
      int fo = kk ? fo1 : fo0;
      bf16x8 af[4], bfr[4];
#pragma unroll
      for (int i = 0; i < 4; i++) {
        af[i] = *(const bf16x8*)&As[(wm + i * 16 + fr) * 64 + fo];
        bfr[i] = *(const bf16x8*)&Bs[(wn + i * 16 + fr) * 64 + fo];
      }
#pragma unroll
      for (int i = 0; i < 4; i++)
#pragma unroll
        for (int j = 0; j < 4; j++)
          acc[i][j] = __builtin_amdgcn_mfma_f32_16x16x32_bf16(af[i], bfr[j], acc[i][j], 0, 0, 0);
    }
  }
  int col = lane & 15, rq = (lane >> 4) * 4;
#pragma unroll
  for (int i = 0; i < 4; i++)
#pragma unroll
    for (int r = 0; r < 4; r++) {
      int slot = m0 + wm + i * 16 + rq + r;
      if (slot < ne) {
#pragma unroll
        for (int j = 0; j < 4; j++) {
          int nn = n0 + wn + j * 16 + col;
          Eout[(size_t)(base + slot) * HDIM + nn] = f2bf(acc[i][j][r]);
        }
      }
    }
}

// ---- combine: Out[tok] += twA*eout[rowA] + twB*eout[rowB]
__global__ __launch_bounds__(256) void combine_kernel(
    const unsigned short* __restrict__ Eout, const int* __restrict__ slotAB,
    const float* __restrict__ twAB, const int* __restrict__ off,
    float* __restrict__ Out) {
  int tok = blockIdx.x, t = threadIdx.x;
  int sa = slotAB[tok * 2], sb = slotAB[tok * 2 + 1];
  float wa = twAB[tok * 2], wb = twAB[tok * 2 + 1];
  int ra = off[sa >> 14] + (sa & 16383);
  int rb = off[sb >> 14] + (sb & 16383);
  const ushort4 a4 = *(const ushort4*)(Eout + (size_t)ra * HDIM + t * 4);
  const ushort4 b4 = *(const ushort4*)(Eout + (size_t)rb * HDIM + t * 4);
  float* po = Out + (size_t)tok * HDIM + t * 4;
  float4 o = *(const float4*)po;
  o.x += wa * bf2f(a4.x) + wb * bf2f(b4.x);
  o.y += wa * bf2f(a4.y) + wb * bf2f(b4.y);
  o.z += wa * bf2f(a4.z) + wb * bf2f(b4.z);
  o.w += wa * bf2f(a4.w) + wb * bf2f(b4.w);
  *(float4*)po = o;
}

extern "C" void kernel_launch(void* const* d_in, const int* in_sizes, int n_in,
                              void* d_out, int out_size, void* d_ws, size_t ws_size,
                              hipStream_t stream) {
  const float* X   = (const float*)d_in[0];
  const float* GW  = (const float*)d_in[1];
  const float* WGU = (const float*)d_in[2];
  const float* WDN = (const float*)d_in[3];
  const float* WSG = (const float*)d_in[4];
  const float* WSU = (const float*)d_in[5];
  const float* WSD = (const float*)d_in[6];
  const float* SEGW = (const float*)d_in[7];
  float* Out = (float*)d_out;
  char* ws = (char*)d_ws;

  unsigned short* xbf  = (unsigned short*)(ws + OFF_XBF);
  unsigned short* wsg  = (unsigned short*)(ws + OFF_WSG);
  unsigned short* wsu  = (unsigned short*)(ws + OFF_WSU);
  unsigned short* wsd  = (unsigned short*)(ws + OFF_WSD);
  unsigned short* sh   = (unsigned short*)(ws + OFF_SH);
  unsigned short* hexp = (unsigned short*)(ws + OFF_HEXP);
  int*   ids  = (int*)(ws + OFF_IDS);
  int*   cnt  = (int*)(ws + OFF_META);
  int*   off  = (int*)(ws + OFF_META + 64);
  float* pps  = (float*)(ws + OFF_META + 144);
  float* sig  = (float*)(ws + OFF_SIG);
  float* lg   = (float*)(ws + OFF_LG);
  int*   slotAB = (int*)(ws + OFF_SLOT);
  float* twAB   = (float*)(ws + OFF_TWAB);
  unsigned short* eout = (unsigned short*)(ws + OFF_SH);  // sh dead after sg2

  const bool roomy = (ws_size >= WS_NEED_ROOMY);
  unsigned short* wgu_bf = (unsigned short*)(ws + (roomy ? OFF_WGU2 : OFF_SH));
  unsigned short* wdn_bf = (unsigned short*)(ws + (roomy ? OFF_WDN2 : OFF_XBF));

  hipMemsetAsync(ws + OFF_META, 0, 256, stream);

  const int c_wsg = (ISH * HDIM) / 4, c_wsd = (HDIM * ISH) / 4;
  const int c_wgu = (NEXP * 2 * IEXP * HDIM) / 4, c_wdn = (NEXP * HDIM * IEXP) / 4;
  if (roomy) {
    int tot = c_wsg * 2 + c_wsd + c_wgu + c_wdn;
    cvt5_kernel<<<(tot + 255) / 256, 256, 0, stream>>>(
        WSG, wsg, c_wsg, WSU, wsu, c_wsg, WSD, wsd, c_wsd,
        WGU, wgu_bf, c_wgu, WDN, wdn_bf, c_wdn);
  } else {
    int tot = c_wsg * 2 + c_wsd;
    cvt5_kernel<<<(tot + 255) / 256, 256, 0, stream>>>(
        WSG, wsg, c_wsg, WSU, wsu, c_wsg, WSD, wsd, c_wsd,
        (const float*)0, (unsigned short*)0, 0, (const float*)0, (unsigned short*)0, 0);
  }

  logits_kernel<<<N_TOK / 4, 256, 0, stream>>>(X, GW, SEGW, lg, xbf);
  route_kernel<<<N_TOK / 256, 256, 0, stream>>>(lg, cnt, pps, ids, slotAB, twAB, sig);
  offs_aux_kernel<<<1, 64, 0, stream>>>(cnt, off, pps, Out + (size_t)N_TOK * HDIM);

  // shared expert
  shared_gemm1_kernel<<<dim3(ISH / 64, N_TOK / 128), 256, 0, stream>>>(xbf, wsg, wsu, sh);
  shared_gemm2_kernel<<<dim3(HDIM / 64, N_TOK / 128), 256, 0, stream>>>(sh, wsd, sig, Out);

  // routed experts
  if (!roomy)
    cvt_kernel<<<(c_wgu + 255) / 256, 256, 0, stream>>>(WGU, wgu_bf, c_wgu);
  exp_gemm1_kernel<<<dim3(IEXP / 64, N_TOK / 128, NEXP), 256, 0, stream>>>(
      xbf, wgu_bf, ids, cnt, off, hexp);
  if (!roomy)
    cvt_kernel<<<(c_wdn + 255) / 256, 256, 0, stream>>>(WDN, wdn_bf, c_wdn);
  exp_gemm2_kernel<<<dim3(HDIM / 128, N_TOK / 128, NEXP), 256, 0, stream>>>(
      hexp, wdn_bf, cnt, off, eout);
  combine_kernel<<<N_TOK, 256, 0, stream>>>(eout, slotAB, twAB, off, Out);
}